// Round 5
// baseline (443.672 us; speedup 1.0000x reference)
//
#include <hip/hip_runtime.h>
#include <hip/hip_bf16.h>
#include <math.h>

// LSMDecoder: out = sigmoid(bias - wg*N*dist_gam - wd*N*dist_del), plus zd/gd_raw/dd_raw.
// x[i,j] = cvec_i - bco_j - N * dot(A_i, B_j), 512-dim fp16 stacks, fp32 MFMA accumulate.
// Diagonal overridden exactly. R5: build_stacks merged into gemm3 epilogue (one less kernel +
// 12.6MB round-trip); non-temporal stores on out/zd/gd/dd to stop the 268MB stream evicting
// the L2-resident Afp/Bfp stacks that pair's K-loop re-reads.

#define NSZ 8192
#define DLAT 128

typedef _Float16 half8 __attribute__((ext_vector_type(8)));
typedef float f32x4 __attribute__((ext_vector_type(4)));

__device__ __forceinline__ void gl_lds16(const void* g, void* l) {
    __builtin_amdgcn_global_load_lds(
        (const __attribute__((address_space(1))) void*)g,
        (__attribute__((address_space(3))) void*)l, 16, 0, 0);
}

__device__ __forceinline__ float fast_sigmoid(float x) {
    float e = __builtin_amdgcn_exp2f(-1.44269504f * x);
    return __builtin_amdgcn_rcpf(1.0f + e);
}

// ---------------- P1: column softmax of Wz/Wg/Wd -> transposed fp16 tables ------------------
__global__ void softmax_cols(const float* __restrict__ Wz, const float* __restrict__ Wg,
                             const float* __restrict__ Wd, _Float16* __restrict__ Tt) {
    int col = blockIdx.x & 127;
    int m = blockIdx.x >> 7;
    const float* W = (m == 0) ? Wz : (m == 1 ? Wg : Wd);
    _Float16* To = Tt + (size_t)m * 65536 + (size_t)col * 512;
    int l = threadIdx.x;  // 64 threads = 1 wave
    float v[8];
    float mx = -3.4e38f;
    for (int i = 0; i < 8; ++i) {
        v[i] = W[(size_t)(i * 64 + l) * 128 + col];
        mx = fmaxf(mx, v[i]);
    }
    for (int off = 32; off; off >>= 1) mx = fmaxf(mx, __shfl_xor(mx, off));
    float s = 0.f;
    for (int i = 0; i < 8; ++i) { v[i] = expf(v[i] - mx); s += v[i]; }
    for (int off = 32; off; off >>= 1) s += __shfl_xor(s, off);
    float inv = 1.0f / s;
    for (int i = 0; i < 8; ++i) To[i * 64 + l] = (_Float16)(v[i] * inv);
}

// ---------------- P2: fused fp16 MFMA GEMM (zd/gd/dd) + stack build + row scalars -----------
// 16-row blocks (512 blocks), 128 thr = 2 waves; both waves share the 16 rows, wave w takes
// j-cols [w*64, w*64+64). Loops m=0..2 over {z,gamma,delta}; zd/gd kept in registers, dd in
// acc; epilogue builds Afp/Bfp fp16 stacks + cvec/bco without touching global zd again.
__global__ __launch_bounds__(128) void gemm3_build(
        const float* __restrict__ z, const float* __restrict__ gamma,
        const float* __restrict__ delta, const _Float16* __restrict__ Tt,
        float* __restrict__ outTail, _Float16* __restrict__ Afp, _Float16* __restrict__ Bfp,
        float* __restrict__ cvec, float* __restrict__ bco,
        const float* __restrict__ pb, const float* __restrict__ pwg,
        const float* __restrict__ pwd) {
    int rowBase = blockIdx.x * 16;
    __shared__ _Float16 As[16 * 520];     // 16.3 KB, row stride 520 halves
    __shared__ float reds_a[16][2], reds_b[16][2];
    int t = threadIdx.x;
    int l = t & 63, w = t >> 6;
    int lc = l & 15, lq = l >> 4;
    float wg = *pwg, wd = *pwd, bias = *pb;

    float vz[4][4], vg[4][4];
    f32x4 acc[4];

    for (int m = 0; m < 3; ++m) {
        const float* A = (m == 0) ? z : (m == 1 ? gamma : delta);
        const _Float16* B = Tt + (size_t)m * 65536;
        __syncthreads();   // previous phase's LDS reads done
        for (int s = 0; s < 8; ++s) {     // stage 16 rows x 512 k, fp32 -> fp16
            int id = s * 128 + t;
            int row = id >> 6, c8 = id & 63;
            const float4* src = (const float4*)(A + (size_t)(rowBase + row) * 512 + c8 * 8);
            float4 f0 = src[0], f1 = src[1];
            half8 h = {(_Float16)f0.x, (_Float16)f0.y, (_Float16)f0.z, (_Float16)f0.w,
                       (_Float16)f1.x, (_Float16)f1.y, (_Float16)f1.z, (_Float16)f1.w};
            *(half8*)(&As[row * 520 + c8 * 8]) = h;
        }
        __syncthreads();
        for (int ni = 0; ni < 4; ++ni) acc[ni] = (f32x4){0.f, 0.f, 0.f, 0.f};
        for (int kt = 0; kt < 16; ++kt) {
            int k0 = kt * 32;
            half8 af = *(const half8*)(&As[lc * 520 + k0 + lq * 8]);
            for (int ni = 0; ni < 4; ++ni) {
                int j = w * 64 + ni * 16 + lc;
                half8 bf = *(const half8*)(B + (size_t)j * 512 + k0 + lq * 8);
                acc[ni] = __builtin_amdgcn_mfma_f32_16x16x32_f16(af, bf, acc[ni], 0, 0, 0);
            }
        }
        float* C = outTail + (size_t)m * (NSZ * DLAT);
        for (int ni = 0; ni < 4; ++ni) {
            for (int r = 0; r < 4; ++r) {
                int row = rowBase + lq * 4 + r;        // C/D: row = quad*4+reg
                int col = w * 64 + ni * 16 + lc;       // C/D: col = lane&15
                __builtin_nontemporal_store(acc[ni][r], &C[(size_t)row * 128 + col]);
                if (m == 0) vz[ni][r] = acc[ni][r];
                else if (m == 1) vg[ni][r] = acc[ni][r];
            }
        }
    }

    // epilogue: build stacks + row scalars. lane position (r,ni): i=rowBase+lq*4+r, k=w*64+ni*16+lc
    float pa[4] = {0.f, 0.f, 0.f, 0.f}, pbv[4] = {0.f, 0.f, 0.f, 0.f};
    for (int ni = 0; ni < 4; ++ni) {
        for (int r = 0; r < 4; ++r) {
            int i = rowBase + lq * 4 + r;
            int k = w * 64 + ni * 16 + lc;
            float zv = vz[ni][r];
            float g = vg[ni][r] + 1e-16f;
            float d = acc[ni][r] + 1e-16f;
            float z2 = zv * zv;
            float u = 1.0f / g, p = 1.0f / d;
            _Float16* Ar = Afp + (size_t)i * 512;
            _Float16* Br = Bfp + (size_t)i * 512;
            Ar[k]       = (_Float16)(wg * u);
            Ar[128 + k] = (_Float16)(wg * zv * u);
            Ar[256 + k] = (_Float16)(wd * z2);
            Ar[384 + k] = (_Float16)(wd * zv);
            Br[k]       = (_Float16)(z2);
            Br[128 + k] = (_Float16)(-2.0f * zv);
            Br[256 + k] = (_Float16)(p);
            Br[384 + k] = (_Float16)(-2.0f * zv * p);
            pa[r] += z2 * u;
            pbv[r] += z2 * p;
        }
    }
    for (int r = 0; r < 4; ++r) {     // reduce across lc (16 lanes)
        for (int off = 8; off; off >>= 1) {
            pa[r] += __shfl_xor(pa[r], off);
            pbv[r] += __shfl_xor(pbv[r], off);
        }
    }
    if (lc == 0) {
        for (int r = 0; r < 4; ++r) {
            reds_a[lq * 4 + r][w] = pa[r];
            reds_b[lq * 4 + r][w] = pbv[r];
        }
    }
    __syncthreads();
    if (t < 16) {
        cvec[rowBase + t] = bias - 8192.0f * wg * (reds_a[t][0] + reds_a[t][1]);
        bco[rowBase + t] = 8192.0f * wd * (reds_b[t][0] + reds_b[t][1]);
    }
}

// ---------------- P3: fp16 MFMA pair kernel, 128x128 tile, K=512, fused sigmoid -------------
// LDS layout: per matrix 128 rows x 8 chunks of 16B, slot(r,q) = r*8 + (q ^ (r&7)).
// Staged via global_load_lds (wave-uniform LDS base + lane*16).
__global__ __launch_bounds__(256) void pair_kernel(const _Float16* __restrict__ Afp,
                                                   const _Float16* __restrict__ Bfp,
                                                   const float* __restrict__ cvec,
                                                   const float* __restrict__ bco,
                                                   const float* __restrict__ pbias,
                                                   float* __restrict__ out) {
    int bid = blockIdx.x;
    int super = bid >> 6, within = bid & 63;
    int sy = super >> 3, sx = super & 7;
    int by = sy * 8 + (within >> 3), bx = sx * 8 + (within & 7);
    int iBase = by * 128, jBase = bx * 128;

    __shared__ _Float16 As[128 * 64];  // 16 KB, XOR-swizzled chunks
    __shared__ _Float16 Bs[128 * 64];
    int t = threadIdx.x;
    int l = t & 63, w = t >> 6;
    int wm = (w >> 1) * 64, wn = (w & 1) * 64;
    int lc = l & 15, lq = l >> 4;
    f32x4 acc[4][4] = {};

    int srow = l >> 3;                 // 0..7 row within the 8-row group
    int sq = (l & 7) ^ srow;           // permuted chunk index within the row

    for (int kt = 0; kt < 8; ++kt) {
        int k0 = kt * 64;
        for (int s = 0; s < 4; ++s) {
            int rr = (w * 4 + s) * 8 + srow;
            const _Float16* ga = Afp + (size_t)(iBase + rr) * 512 + k0 + sq * 8;
            const _Float16* gb = Bfp + (size_t)(jBase + rr) * 512 + k0 + sq * 8;
            gl_lds16(ga, &As[(w * 4 + s) * 512]);
            gl_lds16(gb, &Bs[(w * 4 + s) * 512]);
        }
        __syncthreads();
        for (int ks = 0; ks < 2; ++ks) {
            half8 af[4], bf[4];
            for (int mi = 0; mi < 4; ++mi) {
                int r = wm + mi * 16 + lc;
                int q = ks * 4 + lq;
                af[mi] = *(const half8*)(&As[((r << 3) + (q ^ (r & 7))) << 3]);
            }
            for (int ni = 0; ni < 4; ++ni) {
                int r = wn + ni * 16 + lc;
                int q = ks * 4 + lq;
                bf[ni] = *(const half8*)(&Bs[((r << 3) + (q ^ (r & 7))) << 3]);
            }
            for (int mi = 0; mi < 4; ++mi)
                for (int ni = 0; ni < 4; ++ni)
                    acc[mi][ni] = __builtin_amdgcn_mfma_f32_16x16x32_f16(af[mi], bf[ni],
                                                                         acc[mi][ni], 0, 0, 0);
        }
        __syncthreads();
    }

    float bias = *pbias;
    float civ[4][4], bjv[4];
    for (int mi = 0; mi < 4; ++mi)
        for (int r = 0; r < 4; ++r)
            civ[mi][r] = cvec[iBase + wm + mi * 16 + lq * 4 + r];
    for (int ni = 0; ni < 4; ++ni) bjv[ni] = bco[jBase + wn + ni * 16 + lc];

    for (int mi = 0; mi < 4; ++mi) {
        for (int ni = 0; ni < 4; ++ni) {
            for (int r = 0; r < 4; ++r) {
                int i = iBase + wm + mi * 16 + lq * 4 + r;
                int j = jBase + wn + ni * 16 + lc;
                float x = civ[mi][r] - bjv[ni] - 8192.0f * acc[mi][ni][r];
                if (i == j) x = bias;                        // exact diagonal (dist == 0)
                __builtin_nontemporal_store(fast_sigmoid(x), &out[(size_t)i * NSZ + j]);
            }
        }
    }
}

extern "C" void kernel_launch(void* const* d_in, const int* in_sizes, int n_in,
                              void* d_out, int out_size, void* d_ws, size_t ws_size,
                              hipStream_t stream) {
    const float* z = (const float*)d_in[0];
    const float* gamma = (const float*)d_in[1];
    const float* delta = (const float*)d_in[2];
    const float* Wz = (const float*)d_in[3];
    const float* Wg = (const float*)d_in[4];
    const float* Wd = (const float*)d_in[5];
    const float* pb = (const float*)d_in[6];
    const float* pwg = (const float*)d_in[7];
    const float* pwd = (const float*)d_in[8];

    float* out = (float*)d_out;
    float* zd_out = out + (size_t)NSZ * NSZ;

    float* wsf = (float*)d_ws;
    _Float16* Tt = (_Float16*)wsf;        // 3*512*128 fp16 = 384 KB (transposed tables)
    float* cvec = wsf + 98304;
    float* bco = cvec + 8192;
    _Float16* Afp = (_Float16*)(bco + 8192);          // 16B aligned; 8 MB
    _Float16* Bfp = Afp + (size_t)NSZ * 512;          // 8 MB

    softmax_cols<<<384, 64, 0, stream>>>(Wz, Wg, Wd, Tt);
    gemm3_build<<<512, 128, 0, stream>>>(z, gamma, delta, Tt, zd_out, Afp, Bfp,
                                         cvec, bco, pb, pwg, pwd);
    pair_kernel<<<4096, 256, 0, stream>>>(Afp, Bfp, cvec, bco, pb, out);
}

// Round 6
// 433.853 us; speedup vs baseline: 1.0226x; 1.0226x over previous
//
#include <hip/hip_runtime.h>
#include <hip/hip_bf16.h>
#include <math.h>

// LSMDecoder: out = sigmoid(bias - wg*N*dist_gam - wd*N*dist_del), plus zd/gd_raw/dd_raw.
// x[i,j] = cvec_i - bco_j - N * dot(A_i, B_j), 512-dim fp16 stacks, fp32 MFMA accumulate.
// Diagonal overridden exactly. R6: revert ALL nontemporal stores (R5's nt on the 268MB out
// stream bypassed L2 write-combining -> partial-line HBM bursts, +30-45us). Keep R5's
// gemm3+build_stacks fusion.

#define NSZ 8192
#define DLAT 128

typedef _Float16 half8 __attribute__((ext_vector_type(8)));
typedef float f32x4 __attribute__((ext_vector_type(4)));

__device__ __forceinline__ void gl_lds16(const void* g, void* l) {
    __builtin_amdgcn_global_load_lds(
        (const __attribute__((address_space(1))) void*)g,
        (__attribute__((address_space(3))) void*)l, 16, 0, 0);
}

__device__ __forceinline__ float fast_sigmoid(float x) {
    float e = __builtin_amdgcn_exp2f(-1.44269504f * x);
    return __builtin_amdgcn_rcpf(1.0f + e);
}

// ---------------- P1: column softmax of Wz/Wg/Wd -> transposed fp16 tables ------------------
__global__ void softmax_cols(const float* __restrict__ Wz, const float* __restrict__ Wg,
                             const float* __restrict__ Wd, _Float16* __restrict__ Tt) {
    int col = blockIdx.x & 127;
    int m = blockIdx.x >> 7;
    const float* W = (m == 0) ? Wz : (m == 1 ? Wg : Wd);
    _Float16* To = Tt + (size_t)m * 65536 + (size_t)col * 512;
    int l = threadIdx.x;  // 64 threads = 1 wave
    float v[8];
    float mx = -3.4e38f;
    for (int i = 0; i < 8; ++i) {
        v[i] = W[(size_t)(i * 64 + l) * 128 + col];
        mx = fmaxf(mx, v[i]);
    }
    for (int off = 32; off; off >>= 1) mx = fmaxf(mx, __shfl_xor(mx, off));
    float s = 0.f;
    for (int i = 0; i < 8; ++i) { v[i] = expf(v[i] - mx); s += v[i]; }
    for (int off = 32; off; off >>= 1) s += __shfl_xor(s, off);
    float inv = 1.0f / s;
    for (int i = 0; i < 8; ++i) To[i * 64 + l] = (_Float16)(v[i] * inv);
}

// ---------------- P2: fused fp16 MFMA GEMM (zd/gd/dd) + stack build + row scalars -----------
// 16-row blocks (512 blocks), 128 thr = 2 waves; wave w takes j-cols [w*64, w*64+64).
// Loops m=0..2 over {z,gamma,delta}; zd/gd kept in registers, dd in acc; epilogue builds
// Afp/Bfp fp16 stacks + cvec/bco without re-reading zd from global.
__global__ __launch_bounds__(128) void gemm3_build(
        const float* __restrict__ z, const float* __restrict__ gamma,
        const float* __restrict__ delta, const _Float16* __restrict__ Tt,
        float* __restrict__ outTail, _Float16* __restrict__ Afp, _Float16* __restrict__ Bfp,
        float* __restrict__ cvec, float* __restrict__ bco,
        const float* __restrict__ pb, const float* __restrict__ pwg,
        const float* __restrict__ pwd) {
    int rowBase = blockIdx.x * 16;
    __shared__ _Float16 As[16 * 520];     // 16.3 KB, row stride 520 halves
    __shared__ float reds_a[16][2], reds_b[16][2];
    int t = threadIdx.x;
    int l = t & 63, w = t >> 6;
    int lc = l & 15, lq = l >> 4;
    float wg = *pwg, wd = *pwd, bias = *pb;

    float vz[4][4], vg[4][4];
    f32x4 acc[4];

    for (int m = 0; m < 3; ++m) {
        const float* A = (m == 0) ? z : (m == 1 ? gamma : delta);
        const _Float16* B = Tt + (size_t)m * 65536;
        __syncthreads();   // previous phase's LDS reads done
        for (int s = 0; s < 8; ++s) {     // stage 16 rows x 512 k, fp32 -> fp16
            int id = s * 128 + t;
            int row = id >> 6, c8 = id & 63;
            const float4* src = (const float4*)(A + (size_t)(rowBase + row) * 512 + c8 * 8);
            float4 f0 = src[0], f1 = src[1];
            half8 h = {(_Float16)f0.x, (_Float16)f0.y, (_Float16)f0.z, (_Float16)f0.w,
                       (_Float16)f1.x, (_Float16)f1.y, (_Float16)f1.z, (_Float16)f1.w};
            *(half8*)(&As[row * 520 + c8 * 8]) = h;
        }
        __syncthreads();
        for (int ni = 0; ni < 4; ++ni) acc[ni] = (f32x4){0.f, 0.f, 0.f, 0.f};
        for (int kt = 0; kt < 16; ++kt) {
            int k0 = kt * 32;
            half8 af = *(const half8*)(&As[lc * 520 + k0 + lq * 8]);
            for (int ni = 0; ni < 4; ++ni) {
                int j = w * 64 + ni * 16 + lc;
                half8 bf = *(const half8*)(B + (size_t)j * 512 + k0 + lq * 8);
                acc[ni] = __builtin_amdgcn_mfma_f32_16x16x32_f16(af, bf, acc[ni], 0, 0, 0);
            }
        }
        float* C = outTail + (size_t)m * (NSZ * DLAT);
        for (int ni = 0; ni < 4; ++ni) {
            for (int r = 0; r < 4; ++r) {
                int row = rowBase + lq * 4 + r;        // C/D: row = quad*4+reg
                int col = w * 64 + ni * 16 + lc;       // C/D: col = lane&15
                C[(size_t)row * 128 + col] = acc[ni][r];
                if (m == 0) vz[ni][r] = acc[ni][r];
                else if (m == 1) vg[ni][r] = acc[ni][r];
            }
        }
    }

    // epilogue: build stacks + row scalars. lane (r,ni): i=rowBase+lq*4+r, k=w*64+ni*16+lc
    float pa[4] = {0.f, 0.f, 0.f, 0.f}, pbv[4] = {0.f, 0.f, 0.f, 0.f};
    for (int ni = 0; ni < 4; ++ni) {
        for (int r = 0; r < 4; ++r) {
            int i = rowBase + lq * 4 + r;
            int k = w * 64 + ni * 16 + lc;
            float zv = vz[ni][r];
            float g = vg[ni][r] + 1e-16f;
            float d = acc[ni][r] + 1e-16f;
            float z2 = zv * zv;
            float u = 1.0f / g, p = 1.0f / d;
            _Float16* Ar = Afp + (size_t)i * 512;
            _Float16* Br = Bfp + (size_t)i * 512;
            Ar[k]       = (_Float16)(wg * u);
            Ar[128 + k] = (_Float16)(wg * zv * u);
            Ar[256 + k] = (_Float16)(wd * z2);
            Ar[384 + k] = (_Float16)(wd * zv);
            Br[k]       = (_Float16)(z2);
            Br[128 + k] = (_Float16)(-2.0f * zv);
            Br[256 + k] = (_Float16)(p);
            Br[384 + k] = (_Float16)(-2.0f * zv * p);
            pa[r] += z2 * u;
            pbv[r] += z2 * p;
        }
    }
    for (int r = 0; r < 4; ++r) {     // reduce across lc (16 lanes)
        for (int off = 8; off; off >>= 1) {
            pa[r] += __shfl_xor(pa[r], off);
            pbv[r] += __shfl_xor(pbv[r], off);
        }
    }
    if (lc == 0) {
        for (int r = 0; r < 4; ++r) {
            reds_a[lq * 4 + r][w] = pa[r];
            reds_b[lq * 4 + r][w] = pbv[r];
        }
    }
    __syncthreads();
    if (t < 16) {
        cvec[rowBase + t] = bias - 8192.0f * wg * (reds_a[t][0] + reds_a[t][1]);
        bco[rowBase + t] = 8192.0f * wd * (reds_b[t][0] + reds_b[t][1]);
    }
}

// ---------------- P3: fp16 MFMA pair kernel, 128x128 tile, K=512, fused sigmoid -------------
// LDS layout: per matrix 128 rows x 8 chunks of 16B, slot(r,q) = r*8 + (q ^ (r&7)).
// Staged via global_load_lds (wave-uniform LDS base + lane*16).
__global__ __launch_bounds__(256) void pair_kernel(const _Float16* __restrict__ Afp,
                                                   const _Float16* __restrict__ Bfp,
                                                   const float* __restrict__ cvec,
                                                   const float* __restrict__ bco,
                                                   const float* __restrict__ pbias,
                                                   float* __restrict__ out) {
    int bid = blockIdx.x;
    int super = bid >> 6, within = bid & 63;
    int sy = super >> 3, sx = super & 7;
    int by = sy * 8 + (within >> 3), bx = sx * 8 + (within & 7);
    int iBase = by * 128, jBase = bx * 128;

    __shared__ _Float16 As[128 * 64];  // 16 KB, XOR-swizzled chunks
    __shared__ _Float16 Bs[128 * 64];
    int t = threadIdx.x;
    int l = t & 63, w = t >> 6;
    int wm = (w >> 1) * 64, wn = (w & 1) * 64;
    int lc = l & 15, lq = l >> 4;
    f32x4 acc[4][4] = {};

    int srow = l >> 3;                 // 0..7 row within the 8-row group
    int sq = (l & 7) ^ srow;           // permuted chunk index within the row

    for (int kt = 0; kt < 8; ++kt) {
        int k0 = kt * 64;
        for (int s = 0; s < 4; ++s) {
            int rr = (w * 4 + s) * 8 + srow;
            const _Float16* ga = Afp + (size_t)(iBase + rr) * 512 + k0 + sq * 8;
            const _Float16* gb = Bfp + (size_t)(jBase + rr) * 512 + k0 + sq * 8;
            gl_lds16(ga, &As[(w * 4 + s) * 512]);
            gl_lds16(gb, &Bs[(w * 4 + s) * 512]);
        }
        __syncthreads();
        for (int ks = 0; ks < 2; ++ks) {
            half8 af[4], bf[4];
            for (int mi = 0; mi < 4; ++mi) {
                int r = wm + mi * 16 + lc;
                int q = ks * 4 + lq;
                af[mi] = *(const half8*)(&As[((r << 3) + (q ^ (r & 7))) << 3]);
            }
            for (int ni = 0; ni < 4; ++ni) {
                int r = wn + ni * 16 + lc;
                int q = ks * 4 + lq;
                bf[ni] = *(const half8*)(&Bs[((r << 3) + (q ^ (r & 7))) << 3]);
            }
            for (int mi = 0; mi < 4; ++mi)
                for (int ni = 0; ni < 4; ++ni)
                    acc[mi][ni] = __builtin_amdgcn_mfma_f32_16x16x32_f16(af[mi], bf[ni],
                                                                         acc[mi][ni], 0, 0, 0);
        }
        __syncthreads();
    }

    float bias = *pbias;
    float civ[4][4], bjv[4];
    for (int mi = 0; mi < 4; ++mi)
        for (int r = 0; r < 4; ++r)
            civ[mi][r] = cvec[iBase + wm + mi * 16 + lq * 4 + r];
    for (int ni = 0; ni < 4; ++ni) bjv[ni] = bco[jBase + wn + ni * 16 + lc];

    for (int mi = 0; mi < 4; ++mi) {
        for (int ni = 0; ni < 4; ++ni) {
            for (int r = 0; r < 4; ++r) {
                int i = iBase + wm + mi * 16 + lq * 4 + r;
                int j = jBase + wn + ni * 16 + lc;
                float x = civ[mi][r] - bjv[ni] - 8192.0f * acc[mi][ni][r];
                if (i == j) x = bias;                        // exact diagonal (dist == 0)
                out[(size_t)i * NSZ + j] = fast_sigmoid(x);
            }
        }
    }
}

extern "C" void kernel_launch(void* const* d_in, const int* in_sizes, int n_in,
                              void* d_out, int out_size, void* d_ws, size_t ws_size,
                              hipStream_t stream) {
    const float* z = (const float*)d_in[0];
    const float* gamma = (const float*)d_in[1];
    const float* delta = (const float*)d_in[2];
    const float* Wz = (const float*)d_in[3];
    const float* Wg = (const float*)d_in[4];
    const float* Wd = (const float*)d_in[5];
    const float* pb = (const float*)d_in[6];
    const float* pwg = (const float*)d_in[7];
    const float* pwd = (const float*)d_in[8];

    float* out = (float*)d_out;
    float* zd_out = out + (size_t)NSZ * NSZ;

    float* wsf = (float*)d_ws;
    _Float16* Tt = (_Float16*)wsf;        // 3*512*128 fp16 = 384 KB (transposed tables)
    float* cvec = wsf + 98304;
    float* bco = cvec + 8192;
    _Float16* Afp = (_Float16*)(bco + 8192);          // 16B aligned; 8 MB
    _Float16* Bfp = Afp + (size_t)NSZ * 512;          // 8 MB

    softmax_cols<<<384, 64, 0, stream>>>(Wz, Wg, Wd, Tt);
    gemm3_build<<<512, 128, 0, stream>>>(z, gamma, delta, Tt, zd_out, Afp, Bfp,
                                         cvec, bco, pb, pwg, pwd);
    pair_kernel<<<4096, 256, 0, stream>>>(Afp, Bfp, cvec, bco, pb, out);
}

// Round 7
// 414.024 us; speedup vs baseline: 1.0716x; 1.0479x over previous
//
#include <hip/hip_runtime.h>
#include <hip/hip_bf16.h>
#include <math.h>

// LSMDecoder: out = sigmoid(bias - wg*N*dist_gam - wd*N*dist_del), plus zd/gd_raw/dd_raw.
// x[i,j] = cvec_i - bco_j - N * dot(A_i, B_j), 512-dim fp16 stacks, fp32 MFMA accumulate.
// Diagonal overridden exactly. R7: revert to R4 structure (separate gemm3_mfma+build_stacks;
// fused epilogue's 32B-segment stack stores cost +5.7us). Pair K-loop -> 32x32x16 MFMA
// (4060 vs 3378 FLOP/cyc/CU, m06) + diagonal check hoisted behind block-uniform branch.

#define NSZ 8192
#define DLAT 128

typedef _Float16 half8 __attribute__((ext_vector_type(8)));
typedef float f32x4 __attribute__((ext_vector_type(4)));
typedef float f32x16 __attribute__((ext_vector_type(16)));

__device__ __forceinline__ void gl_lds16(const void* g, void* l) {
    __builtin_amdgcn_global_load_lds(
        (const __attribute__((address_space(1))) void*)g,
        (__attribute__((address_space(3))) void*)l, 16, 0, 0);
}

__device__ __forceinline__ float fast_sigmoid(float x) {
    float e = __builtin_amdgcn_exp2f(-1.44269504f * x);
    return __builtin_amdgcn_rcpf(1.0f + e);
}

// ---------------- P1: column softmax of Wz/Wg/Wd -> transposed fp16 tables ------------------
__global__ void softmax_cols(const float* __restrict__ Wz, const float* __restrict__ Wg,
                             const float* __restrict__ Wd, _Float16* __restrict__ Tt) {
    int col = blockIdx.x & 127;
    int m = blockIdx.x >> 7;
    const float* W = (m == 0) ? Wz : (m == 1 ? Wg : Wd);
    _Float16* To = Tt + (size_t)m * 65536 + (size_t)col * 512;
    int l = threadIdx.x;  // 64 threads = 1 wave
    float v[8];
    float mx = -3.4e38f;
    for (int i = 0; i < 8; ++i) {
        v[i] = W[(size_t)(i * 64 + l) * 128 + col];
        mx = fmaxf(mx, v[i]);
    }
    for (int off = 32; off; off >>= 1) mx = fmaxf(mx, __shfl_xor(mx, off));
    float s = 0.f;
    for (int i = 0; i < 8; ++i) { v[i] = expf(v[i] - mx); s += v[i]; }
    for (int off = 32; off; off >>= 1) s += __shfl_xor(s, off);
    float inv = 1.0f / s;
    for (int i = 0; i < 8; ++i) To[i * 64 + l] = (_Float16)(v[i] * inv);
}

// ---------------- P2: fp16 MFMA GEMM  [8192x512] @ [512x128] for zd / gd_raw / dd_raw ------
// 32-row M-tile, 128 threads (2 waves, 16 rows each), full K=512 staged once as fp16 in LDS.
// B-fragments read straight from the L2-resident Tt (128 KB per matrix). 768 blocks = 3/CU.
__global__ __launch_bounds__(128) void gemm3_mfma(const float* __restrict__ z,
                                                  const float* __restrict__ gamma,
                                                  const float* __restrict__ delta,
                                                  const _Float16* __restrict__ Tt,
                                                  float* __restrict__ outTail) {
    int m = blockIdx.y;
    const float* A = (m == 0) ? z : (m == 1 ? gamma : delta);
    const _Float16* B = Tt + (size_t)m * 65536;
    float* C = outTail + (size_t)m * (NSZ * DLAT);
    int rowBase = blockIdx.x * 32;
    __shared__ _Float16 As[32 * 520];   // row stride 520 halves (1040 B), 33.3 KB
    int t = threadIdx.x;
    for (int s = 0; s < 16; ++s) {      // stage+convert: 32 rows x 512 k
        int id = s * 128 + t;
        int row = id >> 6, c8 = id & 63;
        const float4* src = (const float4*)(A + (size_t)(rowBase + row) * 512 + c8 * 8);
        float4 f0 = src[0], f1 = src[1];
        half8 h = {(_Float16)f0.x, (_Float16)f0.y, (_Float16)f0.z, (_Float16)f0.w,
                   (_Float16)f1.x, (_Float16)f1.y, (_Float16)f1.z, (_Float16)f1.w};
        *(half8*)(&As[row * 520 + c8 * 8]) = h;
    }
    __syncthreads();

    int l = t & 63, w = t >> 6;
    int lc = l & 15, lq = l >> 4;
    int m0 = w * 16;                    // wave's 16 rows within tile
    f32x4 acc[8] = {};
    for (int kt = 0; kt < 16; ++kt) {
        int k0 = kt * 32;
        half8 af = *(const half8*)(&As[(m0 + lc) * 520 + k0 + lq * 8]);
        for (int ni = 0; ni < 8; ++ni) {
            half8 bf = *(const half8*)(B + (size_t)(ni * 16 + lc) * 512 + k0 + lq * 8);
            acc[ni] = __builtin_amdgcn_mfma_f32_16x16x32_f16(af, bf, acc[ni], 0, 0, 0);
        }
    }
    for (int ni = 0; ni < 8; ++ni) {
        for (int r = 0; r < 4; ++r) {
            int row = rowBase + m0 + lq * 4 + r;   // C/D: row = quad*4+reg
            int col = ni * 16 + lc;                // C/D: col = lane&15
            C[(size_t)row * 128 + col] = acc[ni][r];
        }
    }
}

// ---------------- P2b: build fp16 stacked A/B [8192x512] + per-row scalars ------------------
__global__ void build_stacks(const float* __restrict__ zd, const float* __restrict__ gdr,
                             const float* __restrict__ ddr, _Float16* __restrict__ Afp,
                             _Float16* __restrict__ Bfp, float* __restrict__ cvec,
                             float* __restrict__ bco, const float* __restrict__ pb,
                             const float* __restrict__ pwg, const float* __restrict__ pwd) {
    int i = blockIdx.x;    // 8192 rows
    int k = threadIdx.x;   // 128
    float zv = zd[(size_t)i * 128 + k];
    float g = gdr[(size_t)i * 128 + k] + 1e-16f;
    float d = ddr[(size_t)i * 128 + k] + 1e-16f;
    float z2 = zv * zv;
    float u = 1.0f / g, p = 1.0f / d;
    float wg = *pwg, wd = *pwd, bias = *pb;
    _Float16* Ar = Afp + (size_t)i * 512;
    _Float16* Br = Bfp + (size_t)i * 512;
    Ar[k]       = (_Float16)(wg * u);
    Ar[128 + k] = (_Float16)(wg * zv * u);
    Ar[256 + k] = (_Float16)(wd * z2);
    Ar[384 + k] = (_Float16)(wd * zv);
    Br[k]       = (_Float16)(z2);
    Br[128 + k] = (_Float16)(-2.0f * zv);
    Br[256 + k] = (_Float16)(p);
    Br[384 + k] = (_Float16)(-2.0f * zv * p);
    float a = z2 * u, b = z2 * p;
    for (int off = 32; off; off >>= 1) { a += __shfl_down(a, off); b += __shfl_down(b, off); }
    __shared__ float sa[2], sb[2];
    if ((k & 63) == 0) { sa[k >> 6] = a; sb[k >> 6] = b; }
    __syncthreads();
    if (k == 0) {
        cvec[i] = bias - 8192.0f * wg * (sa[0] + sa[1]);
        bco[i] = 8192.0f * wd * (sb[0] + sb[1]);
    }
}

// ---------------- P3: fp16 MFMA pair kernel, 128x128 tile, K=512, 32x32x16, fused sigmoid ---
// LDS layout: per matrix 128 rows x 8 chunks of 16B, slot(r,q) = r*8 + (q ^ (r&7)).
// Staged via global_load_lds (wave-uniform LDS base + lane*16).
// A/B operand layout 32x32x16: row/col = lane&31, k = (lane>>5)*8 + j.
// C/D layout 32x32 (m74/m101): col = lane&31, row = (reg&3) + 8*(reg>>2) + 4*(lane>>5).
__global__ __launch_bounds__(256) void pair_kernel(const _Float16* __restrict__ Afp,
                                                   const _Float16* __restrict__ Bfp,
                                                   const float* __restrict__ cvec,
                                                   const float* __restrict__ bco,
                                                   const float* __restrict__ pbias,
                                                   float* __restrict__ out) {
    int bid = blockIdx.x;
    int super = bid >> 6, within = bid & 63;
    int sy = super >> 3, sx = super & 7;
    int by = sy * 8 + (within >> 3), bx = sx * 8 + (within & 7);
    int iBase = by * 128, jBase = bx * 128;

    __shared__ _Float16 As[128 * 64];  // 16 KB, XOR-swizzled chunks
    __shared__ _Float16 Bs[128 * 64];
    int t = threadIdx.x;
    int l = t & 63, w = t >> 6;
    int wm = (w >> 1) * 64, wn = (w & 1) * 64;
    int ln = l & 31, lh = l >> 5;
    f32x16 acc[2][2] = {};

    int srow = l >> 3;                 // 0..7 row within the 8-row group
    int sq = (l & 7) ^ srow;           // permuted chunk index within the row

    for (int kt = 0; kt < 8; ++kt) {
        int k0 = kt * 64;
        for (int s = 0; s < 4; ++s) {
            int rr = (w * 4 + s) * 8 + srow;
            const _Float16* ga = Afp + (size_t)(iBase + rr) * 512 + k0 + sq * 8;
            const _Float16* gb = Bfp + (size_t)(jBase + rr) * 512 + k0 + sq * 8;
            gl_lds16(ga, &As[(w * 4 + s) * 512]);
            gl_lds16(gb, &Bs[(w * 4 + s) * 512]);
        }
        __syncthreads();
        for (int ks = 0; ks < 4; ++ks) {   // K=16 per step
            int q = ks * 2 + lh;           // 16B chunk index within the 64-k stage
            half8 af[2], bf[2];
            for (int m2 = 0; m2 < 2; ++m2) {
                int r = wm + m2 * 32 + ln;
                af[m2] = *(const half8*)(&As[((r << 3) + (q ^ (r & 7))) << 3]);
            }
            for (int n2 = 0; n2 < 2; ++n2) {
                int r = wn + n2 * 32 + ln;
                bf[n2] = *(const half8*)(&Bs[((r << 3) + (q ^ (r & 7))) << 3]);
            }
            for (int m2 = 0; m2 < 2; ++m2)
                for (int n2 = 0; n2 < 2; ++n2)
                    acc[m2][n2] = __builtin_amdgcn_mfma_f32_32x32x16_f16(af[m2], bf[n2],
                                                                         acc[m2][n2], 0, 0, 0);
        }
        __syncthreads();
    }

    float bias = *pbias;
    bool diagBlock = (iBase == jBase);
    float bjv[2];
    for (int n2 = 0; n2 < 2; ++n2) bjv[n2] = bco[jBase + wn + n2 * 32 + ln];

    for (int m2 = 0; m2 < 2; ++m2) {
        float civ[16];
        for (int reg = 0; reg < 16; ++reg)
            civ[reg] = cvec[iBase + wm + m2 * 32 + (reg & 3) + 8 * (reg >> 2) + 4 * lh];
        for (int n2 = 0; n2 < 2; ++n2) {
            int j = jBase + wn + n2 * 32 + ln;
            for (int reg = 0; reg < 16; ++reg) {
                int i = iBase + wm + m2 * 32 + (reg & 3) + 8 * (reg >> 2) + 4 * lh;
                float x = civ[reg] - bjv[n2] - 8192.0f * acc[m2][n2][reg];
                if (diagBlock) { if (i == j) x = bias; }     // uniform outer branch
                out[(size_t)i * NSZ + j] = fast_sigmoid(x);
            }
        }
    }
}

extern "C" void kernel_launch(void* const* d_in, const int* in_sizes, int n_in,
                              void* d_out, int out_size, void* d_ws, size_t ws_size,
                              hipStream_t stream) {
    const float* z = (const float*)d_in[0];
    const float* gamma = (const float*)d_in[1];
    const float* delta = (const float*)d_in[2];
    const float* Wz = (const float*)d_in[3];
    const float* Wg = (const float*)d_in[4];
    const float* Wd = (const float*)d_in[5];
    const float* pb = (const float*)d_in[6];
    const float* pwg = (const float*)d_in[7];
    const float* pwd = (const float*)d_in[8];

    float* out = (float*)d_out;
    float* zd_out = out + (size_t)NSZ * NSZ;
    float* gd_out = zd_out + (size_t)NSZ * DLAT;
    float* dd_out = gd_out + (size_t)NSZ * DLAT;

    float* wsf = (float*)d_ws;
    _Float16* Tt = (_Float16*)wsf;        // 3*512*128 fp16 = 384 KB (transposed tables)
    float* cvec = wsf + 98304;
    float* bco = cvec + 8192;
    _Float16* Afp = (_Float16*)(bco + 8192);          // 16B aligned; 8 MB
    _Float16* Bfp = Afp + (size_t)NSZ * 512;          // 8 MB

    softmax_cols<<<384, 64, 0, stream>>>(Wz, Wg, Wd, Tt);
    gemm3_mfma<<<dim3(256, 3), 128, 0, stream>>>(z, gamma, delta, Tt, zd_out);
    build_stacks<<<NSZ, 128, 0, stream>>>(zd_out, gd_out, dd_out, Afp, Bfp, cvec, bco,
                                          pb, pwg, pwd);
    pair_kernel<<<4096, 256, 0, stream>>>(Afp, Bfp, cvec, bco, pb, out);
}